// Round 10
// baseline (199.383 us; speedup 1.0000x reference)
//
#include <hip/hip_runtime.h>

// SSIM loss: Xt, Yt are [B=16, C=1, T=20, H=256, W=256] fp32.
// Frame f = b*20 + t contiguous 65536 floats. dr[t] = max over Yt[:,:,t].
// S per 7x7 valid window (250x250/frame); out = 1 - mean(S).

#define HH 256
#define WW 256
#define OUTW 250
#define NT 20
#define NB 16
#define NFRAMES (NT * NB)        // 320
#define STRIPS 25
#define RPS 10                   // output rows per strip (25*10 = 250)
#define NWAVES (NFRAMES * STRIPS) // 8000
#define WPB 8                    // waves per block (512-thread blocks)
#define NBLK2 (NWAVES / WPB)     // 1000
#define NXCD 8

__device__ __forceinline__ float wave_sum(float v) {
#pragma unroll
    for (int off = 32; off > 0; off >>= 1) v += __shfl_down(v, off, 64);
    return v;
}

// ---------------- Pass 1: per-t max over Yt (quarter-frame blocks) ----------
__global__ __launch_bounds__(256) void dr_max_kernel(const float* __restrict__ Y,
                                                     float* __restrict__ dr_part) {
    int t = blockIdx.x;          // 0..19
    int bq = blockIdx.y;         // 0..63 : b = bq>>2, quarter = bq&3
    const float4* p = (const float4*)(Y + (size_t)((bq >> 2) * NT + t) * (HH * WW))
                      + (bq & 3) * 4096;
    float m = 0.f;               // inputs uniform [0,1) => non-negative
#pragma unroll 4
    for (int k = 0; k < 16; ++k) {
        float4 v = p[k * 256 + threadIdx.x];
        m = fmaxf(m, fmaxf(fmaxf(v.x, v.y), fmaxf(v.z, v.w)));
    }
#pragma unroll
    for (int off = 32; off > 0; off >>= 1) m = fmaxf(m, __shfl_down(m, off, 64));
    __shared__ float smax[4];
    int lane = threadIdx.x & 63, w = threadIdx.x >> 6;
    if (lane == 0) smax[w] = m;
    __syncthreads();
    if (threadIdx.x == 0)
        dr_part[t * 64 + bq] = fmaxf(fmaxf(smax[0], smax[1]), fmaxf(smax[2], smax[3]));
}

// ---------------- Pass 2: SSIM ------------------------------------------
// R15: single-variable amortization experiment on R14's machinery (4 moments,
// raw ds_bpermute hoisted addrs, 2-deep staged loads, XCD swizzle, WPB=8):
// RPS 5->10 (STRIPS 25, 8000 waves, 1000 blocks). At RPS=5 the 7-row prologue
// (~300 VALU, 12 input rows) amortizes over only 5 output rows = 45% of
// per-wave VALU and 2.4 input-rows/output-row; RPS=10 halves both.
// R14 refuted the block-cap theory (512-thr blocks: occupancy still ~33%,
// 51us). 9 structures pinned 51-60us, all pipes <=46% -> amortization is
// the last untested axis; if this also pins ~51, declare roofline.

// S scaled by 49^2 top & bottom (cancels): c1=2401*C1, c2=2401*C2.
// 4-moment form: B2 = cov*(49*hq - hx^2 - hy^2) + c2, hq = 7-tap of sxx+syy.
__device__ __forceinline__ float ssim_px4(float hx, float hy, float hq,
                                          float hxy, float c1, float c2) {
    const float cov = 49.0f / 48.0f;
    float hx2 = hx * hx, hy2 = hy * hy, hxy1 = hx * hy;
    float s2 = hx2 + hy2;
    float A1 = __builtin_fmaf(2.f, hxy1, c1);
    float B1 = s2 + c1;
    float t12 = __builtin_fmaf(49.f, hq, -s2);
    float t3  = __builtin_fmaf(49.f, hxy, -hxy1);
    float A2 = __builtin_fmaf(2.f * cov, t3, c2);
    float B2 = __builtin_fmaf(cov, t12, c2);
    return (A1 * A2) * __builtin_amdgcn_rcpf(B1 * B2);
}

__device__ __forceinline__ float bperm(int addr, float v) {
    return __int_as_float(__builtin_amdgcn_ds_bpermute(addr, __float_as_int(v)));
}

// 7-tap horizontal sums for 4 consecutive output cols; a1/a2 = byte addrs of
// lanes l+1, l+2 (clamped to 63; clamped values feed only masked outputs).
//   P = s.x+s.y+s.z+s.w;  P1 = P(l+1), w1 = s.w(l+1), x2 = s.x(l+2), y2 = s.y(l+2)
//   o0 = P+P1-w1; o1 = P+P1-s.x; o2 = s.z+s.w+P1+x2; o3 = s.w+P1+x2+y2
__device__ __forceinline__ float4 taps7_bp(float4 s, int a1, int a2) {
    float P  = (s.x + s.y) + (s.z + s.w);
    float P1 = bperm(a1, P);
    float w1 = bperm(a1, s.w);
    float x2 = bperm(a2, s.x);
    float y2 = bperm(a2, s.y);
    float base = P + P1;
    float o0 = base - w1;
    float o1 = base - s.x;
    float o2 = s.z + s.w + P1 + x2;
    float o3 = o2 - s.z + y2;          // s.w + P1 + x2 + y2
    return make_float4(o0, o1, o2, o3);
}

// slide with (xn-xo)*(xn+xo) factorization; sq accumulates xx+yy deltas
__device__ __forceinline__ void slide4(float4& sx, float4& sy, float4& sq,
                                       float4& sxy,
                                       float4 xo, float4 yo, float4 xn, float4 yn) {
    float dx, ex, dy, ey;
    dx = xn.x - xo.x; ex = xn.x + xo.x; sx.x += dx; sq.x = __builtin_fmaf(dx, ex, sq.x);
    dy = yn.x - yo.x; ey = yn.x + yo.x; sy.x += dy; sq.x = __builtin_fmaf(dy, ey, sq.x);
    sxy.x += xn.x * yn.x - xo.x * yo.x;
    dx = xn.y - xo.y; ex = xn.y + xo.y; sx.y += dx; sq.y = __builtin_fmaf(dx, ex, sq.y);
    dy = yn.y - yo.y; ey = yn.y + yo.y; sy.y += dy; sq.y = __builtin_fmaf(dy, ey, sq.y);
    sxy.y += xn.y * yn.y - xo.y * yo.y;
    dx = xn.z - xo.z; ex = xn.z + xo.z; sx.z += dx; sq.z = __builtin_fmaf(dx, ex, sq.z);
    dy = yn.z - yo.z; ey = yn.z + yo.z; sy.z += dy; sq.z = __builtin_fmaf(dy, ey, sq.z);
    sxy.z += xn.z * yn.z - xo.z * yo.z;
    dx = xn.w - xo.w; ex = xn.w + xo.w; sx.w += dx; sq.w = __builtin_fmaf(dx, ex, sq.w);
    dy = yn.w - yo.w; ey = yn.w + yo.w; sy.w += dy; sq.w = __builtin_fmaf(dy, ey, sq.w);
    sxy.w += xn.w * yn.w - xo.w * yo.w;
}

__device__ __forceinline__ void accum4(float4& sx, float4& sy, float4& sq,
                                       float4& sxy, float4 xv, float4 yv) {
    sx.x += xv.x; sx.y += xv.y; sx.z += xv.z; sx.w += xv.w;
    sy.x += yv.x; sy.y += yv.y; sy.z += yv.z; sy.w += yv.w;
    sq.x = __builtin_fmaf(xv.x, xv.x, sq.x); sq.x = __builtin_fmaf(yv.x, yv.x, sq.x);
    sq.y = __builtin_fmaf(xv.y, xv.y, sq.y); sq.y = __builtin_fmaf(yv.y, yv.y, sq.y);
    sq.z = __builtin_fmaf(xv.z, xv.z, sq.z); sq.z = __builtin_fmaf(yv.z, yv.z, sq.z);
    sq.w = __builtin_fmaf(xv.w, xv.w, sq.w); sq.w = __builtin_fmaf(yv.w, yv.w, sq.w);
    sxy.x = __builtin_fmaf(xv.x, yv.x, sxy.x); sxy.y = __builtin_fmaf(xv.y, yv.y, sxy.y);
    sxy.z = __builtin_fmaf(xv.z, yv.z, sxy.z); sxy.w = __builtin_fmaf(xv.w, yv.w, sxy.w);
}

__global__ __launch_bounds__(512, 4) void ssim_kernel(const float* __restrict__ X,
                                                      const float* __restrict__ Y,
                                                      const float* __restrict__ dr_part,
                                                      float* __restrict__ partials) {
    int w = threadIdx.x >> 6;   // 0..7
    int l = threadIdx.x & 63;
    // Bijective XCD swizzle (NBLK2 % 8 == 0)
    int bid = blockIdx.x;
    int swz = (bid % NXCD) * (NBLK2 / NXCD) + bid / NXCD;
    int wid = swz * WPB + w;
    int frame = wid / STRIPS;   // 0..319
    int strip = wid % STRIPS;   // 0..24
    int t = frame % NT;
    const float4* x4 = (const float4*)(X + (size_t)frame * (HH * WW));
    const float4* y4 = (const float4*)(Y + (size_t)frame * (HH * WW));
    int c0 = 4 * l;
    // hoisted bpermute byte-addresses (loop-invariant)
    int a1 = (l < 63 ? l + 1 : 63) << 2;
    int a2 = (l < 62 ? l + 2 : 63) << 2;

    // dr[t] = max of the 64 per-block partial maxes (one per lane, butterfly)
    float dr = dr_part[t * 64 + l];
#pragma unroll
    for (int off = 32; off > 0; off >>= 1) dr = fmaxf(dr, __shfl_xor(dr, off, 64));
    float c1 = 2401.f * (0.01f * dr) * (0.01f * dr);
    float c2 = 2401.f * (0.03f * dr) * (0.03f * dr);

    int r0 = strip * RPS;

    // vertical running column-sums (4 cols/lane) over rows r0..r0+6
    float4 sx = make_float4(0, 0, 0, 0), sy = sx, sq = sx, sxy = sx;
#pragma unroll
    for (int dy = 0; dy < 7; ++dy) {
        float4 xv = x4[(r0 + dy) * 64 + l];
        float4 yv = y4[(r0 + dy) * 64 + l];
        accum4(sx, sy, sq, sxy, xv, yv);
    }

    // stage slide-0 loads (rows r0, r0+7)
    float4 cxo = x4[r0 * 64 + l],       cyo = y4[r0 * 64 + l];
    float4 cxn = x4[(r0 + 7) * 64 + l], cyn = y4[(r0 + 7) * 64 + l];

    float acc = 0.f;
#pragma unroll
    for (int it = 0; it < RPS; ++it) {
        // stage slide-(it+1) loads one full iteration ahead of use
        float4 nxo, nyo, nxn, nyn;
        if (it < RPS - 2) {
            int rr = r0 + it + 1;
            nxo = x4[rr * 64 + l];       nyo = y4[rr * 64 + l];
            nxn = x4[(rr + 7) * 64 + l]; nyn = y4[(rr + 7) * 64 + l];
        }
        // pin load issue point: loads above cannot sink below this fence
        asm volatile("" ::: "memory");

        float4 hx  = taps7_bp(sx,  a1, a2);
        float4 hy  = taps7_bp(sy,  a1, a2);
        float4 hq  = taps7_bp(sq,  a1, a2);
        float4 hxy = taps7_bp(sxy, a1, a2);

        // lanes 0..61: all 4 valid; lane 62 (c0=248): 2 valid; lane 63: none
        if (c0 + 0 < OUTW) acc += ssim_px4(hx.x, hy.x, hq.x, hxy.x, c1, c2);
        if (c0 + 1 < OUTW) acc += ssim_px4(hx.y, hy.y, hq.y, hxy.y, c1, c2);
        if (c0 + 2 < OUTW) acc += ssim_px4(hx.z, hy.z, hq.z, hxy.z, c1, c2);
        if (c0 + 3 < OUTW) acc += ssim_px4(hx.w, hy.w, hq.w, hxy.w, c1, c2);

        if (it < RPS - 1)
            slide4(sx, sy, sq, sxy, cxo, cyo, cxn, cyn);
        if (it < RPS - 2) {      // rotate staged set for the next slide
            cxo = nxo; cyo = nyo; cxn = nxn; cyn = nyn;
        }
    }

    // block-level reduction: 8 waves -> 1 partial per block
    acc = wave_sum(acc);
    __shared__ float ssum[WPB];
    if (l == 0) ssum[w] = acc;
    __syncthreads();
    if (threadIdx.x == 0) {
        float s = 0.f;
#pragma unroll
        for (int i = 0; i < WPB; ++i) s += ssum[i];
        partials[blockIdx.x] = s;
    }
}

// ---------------- Pass 3: final reduce ----------------
__global__ __launch_bounds__(256) void final_kernel(const float* __restrict__ partials,
                                                    float* __restrict__ out) {
    float s = 0.f;
    for (int i = threadIdx.x; i < NBLK2; i += 256) s += partials[i];
    s = wave_sum(s);
    __shared__ float ssum[4];
    int lane = threadIdx.x & 63, w = threadIdx.x >> 6;
    if (lane == 0) ssum[w] = s;
    __syncthreads();
    if (threadIdx.x == 0) {
        float total = ssum[0] + ssum[1] + ssum[2] + ssum[3];
        const double denom = (double)NFRAMES * OUTW * OUTW;
        out[0] = (float)(1.0 - (double)total / denom);
    }
}

extern "C" void kernel_launch(void* const* d_in, const int* in_sizes, int n_in,
                              void* d_out, int out_size, void* d_ws, size_t ws_size,
                              hipStream_t stream) {
    const float* X = (const float*)d_in[0];
    const float* Y = (const float*)d_in[1];

    float* ws = (float*)d_ws;
    float* dr_part  = ws;                // [0 .. 1280)
    float* partials = ws + 2048;         // [2048 .. 2048+1000)

    dim3 g1(NT, NB * 4);
    hipLaunchKernelGGL(dr_max_kernel, g1, dim3(256), 0, stream, Y, dr_part);
    hipLaunchKernelGGL(ssim_kernel, dim3(NBLK2), dim3(512), 0, stream,
                       X, Y, (const float*)dr_part, partials);
    hipLaunchKernelGGL(final_kernel, dim3(1), dim3(256), 0, stream,
                       partials, (float*)d_out);
}